// Round 5
// baseline (366.480 us; speedup 1.0000x reference)
//
#include <hip/hip_runtime.h>

#define GN 100000
#define GE 3200000
#define CAP 128
#define NB 391          // coarse buckets: src >> 8, 256 nodes each
#define CHUNK 4096      // edges per bin-pass block
#define BSTRIDE 9216    // fixed bucket stride: mean 8192, sigma ~90, 11-sigma margin
#define GBLK 782        // gemm blocks = ceil(GN/128) == bin blocks = ceil(GE/CHUNK)

typedef __attribute__((ext_vector_type(8))) short bf16x8;
typedef __attribute__((ext_vector_type(4))) float f32x4;

__device__ __forceinline__ unsigned short f2bf(float f) {
    unsigned u = __float_as_uint(f);
    u += 0x7fffu + ((u >> 16) & 1u);          // RNE
    return (unsigned short)(u >> 16);
}
// packed RNE f32x2 -> bf16x2 (1 VALU op vs ~7 for two f2bf)
__device__ __forceinline__ unsigned cvtpk(float lo, float hi) {
    unsigned r;
    asm("v_cvt_pk_bf16_f32 %0, %1, %2" : "=v"(r) : "v"(lo), "v"(hi));
    return r;
}

// ---------------- W prep + bcursor init + s_l/s_r zero (replaces memset) ----------------
__global__ __launch_bounds__(256) void wprep_kernel(const float* __restrict__ w,
                                                    unsigned short* __restrict__ wT,
                                                    int* __restrict__ bcursor,
                                                    float* __restrict__ s_l) {
    if (blockIdx.x < 32) {                          // w fp32 [256][128] -> wT bf16 [128][256]
        int flat4 = blockIdx.x * 256 + threadIdx.x; // 0..8191
        int k  = flat4 >> 5;
        int n4 = (flat4 & 31) * 4;
        float4 v = ((const float4*)w)[flat4];
        wT[(size_t)(n4 + 0) * 256 + k] = f2bf(v.x);
        wT[(size_t)(n4 + 1) * 256 + k] = f2bf(v.y);
        wT[(size_t)(n4 + 2) * 256 + k] = f2bf(v.z);
        wT[(size_t)(n4 + 3) * 256 + k] = f2bf(v.w);
    } else if (blockIdx.x < 34) {                   // bucket cursor init (fixed-stride bases)
        int j = (blockIdx.x - 32) * 256 + threadIdx.x;
        if (j < NB) bcursor[j] = j * BSTRIDE;
    } else {                                        // zero s_l,s_r (contiguous 2*GN floats)
        int i = (blockIdx.x - 34) * 256 + threadIdx.x;
        if (i < 2 * GN / 4) {
            float4 z = {0.f, 0.f, 0.f, 0.f};
            ((float4*)s_l)[i] = z;
        }
    }
}

// ---------------- FAT kernel: gemm (even blocks) || bin (odd blocks) ----------------
// The two halves are dependency-free and resource-orthogonal (MFMA/VALU vs memory+LDS-atomic);
// parity interleave makes every CU host a mixture from the first scheduling round.
__global__ __launch_bounds__(256) void gemmbin_kernel(const float* __restrict__ x,
                                                      const unsigned short* __restrict__ wT,
                                                      const float* __restrict__ a,
                                                      unsigned short* __restrict__ hq,
                                                      float* __restrict__ s_l,
                                                      float* __restrict__ s_r,
                                                      const int* __restrict__ ei,
                                                      int* __restrict__ bcursor,
                                                      unsigned* __restrict__ binned) {
    __shared__ __align__(16) char smem[30848];      // max(gemm 20480, bin 30836)
    const int half = blockIdx.x >> 1;
    const int tid = threadIdx.x;

    if ((blockIdx.x & 1) == 0) {
        // ================= GEMM path: h = x @ W, scores fused =================
        unsigned short (*As)[128][40] = (unsigned short (*)[128][40])smem;
        const int lane = tid & 63, wid = tid >> 6;
        const int l16  = lane & 15, quad = lane >> 4;
        const int wm   = (wid >> 1) * 64, wn = (wid & 1) * 64;
        const int bm   = half * 128;

        f32x4 acc[4][4] = {};

        const int arow = tid >> 1, ahalf = tid & 1;
        int gr = bm + arow; if (gr >= GN) gr = GN - 1;   // clamp loads; stores guarded
        const float* xrow = x + (size_t)gr * 256 + ahalf * 16;

        {   // prologue: stage k0=0 tile into As[0]
            float4 f0 = *(const float4*)(xrow + 0);
            float4 f1 = *(const float4*)(xrow + 4);
            float4 f2 = *(const float4*)(xrow + 8);
            float4 f3 = *(const float4*)(xrow + 12);
            uint4 u0, u1;
            u0.x = cvtpk(f0.x, f0.y); u0.y = cvtpk(f0.z, f0.w);
            u0.z = cvtpk(f1.x, f1.y); u0.w = cvtpk(f1.z, f1.w);
            u1.x = cvtpk(f2.x, f2.y); u1.y = cvtpk(f2.z, f2.w);
            u1.z = cvtpk(f3.x, f3.y); u1.w = cvtpk(f3.z, f3.w);
            *(uint4*)&As[0][arow][ahalf * 16]     = u0;
            *(uint4*)&As[0][arow][ahalf * 16 + 8] = u1;
        }
        bf16x8 bcur[4];
#pragma unroll
        for (int t = 0; t < 4; ++t)
            bcur[t] = *(const bf16x8*)(wT + (size_t)(wn + t * 16 + l16) * 256 + quad * 8);
        __syncthreads();

#pragma unroll
        for (int ks = 0; ks < 8; ++ks) {
            const int cb = ks & 1;
            bf16x8 bnxt[4];
            uint4 u0, u1;
            if (ks < 7) {
                const int k1 = (ks + 1) * 32;
#pragma unroll
                for (int t = 0; t < 4; ++t)
                    bnxt[t] = *(const bf16x8*)(wT + (size_t)(wn + t * 16 + l16) * 256 + k1 + quad * 8);
                float4 f0 = *(const float4*)(xrow + k1);
                float4 f1 = *(const float4*)(xrow + k1 + 4);
                float4 f2 = *(const float4*)(xrow + k1 + 8);
                float4 f3 = *(const float4*)(xrow + k1 + 12);
                u0.x = cvtpk(f0.x, f0.y); u0.y = cvtpk(f0.z, f0.w);
                u0.z = cvtpk(f1.x, f1.y); u0.w = cvtpk(f1.z, f1.w);
                u1.x = cvtpk(f2.x, f2.y); u1.y = cvtpk(f2.z, f2.w);
                u1.z = cvtpk(f3.x, f3.y); u1.w = cvtpk(f3.z, f3.w);
            }
            bf16x8 af[4];
#pragma unroll
            for (int t = 0; t < 4; ++t)
                af[t] = *(const bf16x8*)&As[cb][wm + t * 16 + l16][quad * 8];
#pragma unroll
            for (int ti = 0; ti < 4; ++ti)
#pragma unroll
                for (int tj = 0; tj < 4; ++tj)
                    acc[ti][tj] = __builtin_amdgcn_mfma_f32_16x16x32_bf16(af[ti], bcur[tj], acc[ti][tj], 0, 0, 0);
            if (ks < 7) {
                *(uint4*)&As[cb ^ 1][arow][ahalf * 16]     = u0;
                *(uint4*)&As[cb ^ 1][arow][ahalf * 16 + 8] = u1;
                __syncthreads();
#pragma unroll
                for (int t = 0; t < 4; ++t) bcur[t] = bnxt[t];
            }
        }

        float alv[4], arv[4];
#pragma unroll
        for (int tj = 0; tj < 4; ++tj) {
            alv[tj] = a[wn + tj * 16 + l16];
            arv[tj] = a[128 + wn + tj * 16 + l16];
        }
#pragma unroll
        for (int ti = 0; ti < 4; ++ti) {
            float slp[4], srp[4];
#pragma unroll
            for (int r = 0; r < 4; ++r) {
                int row = bm + wm + ti * 16 + quad * 4 + r;
                float v0 = acc[ti][0][r], v1 = acc[ti][1][r], v2 = acc[ti][2][r], v3 = acc[ti][3][r];
                if (row < GN) {
                    unsigned short* hp = hq + (size_t)row * 128 + wn + l16;
                    hp[0]  = f2bf(v0);
                    hp[16] = f2bf(v1);
                    hp[32] = f2bf(v2);
                    hp[48] = f2bf(v3);
                }
                slp[r] = v0 * alv[0] + v1 * alv[1] + v2 * alv[2] + v3 * alv[3];
                srp[r] = v0 * arv[0] + v1 * arv[1] + v2 * arv[2] + v3 * arv[3];
            }
#pragma unroll
            for (int off = 1; off < 16; off <<= 1)
#pragma unroll
                for (int r = 0; r < 4; ++r) {
                    slp[r] += __shfl_xor(slp[r], off, 64);
                    srp[r] += __shfl_xor(srp[r], off, 64);
                }
            if (l16 == 0) {
#pragma unroll
                for (int r = 0; r < 4; ++r) {
                    int row = bm + wm + ti * 16 + quad * 4 + r;
                    if (row < GN) {
                        atomicAdd(&s_l[row], slp[r]);
                        atomicAdd(&s_r[row], srp[r]);
                    }
                }
            }
        }
    } else {
        // ================= BIN path: per-chunk counting sort -> coalesced runs =================
        // entry = (srcLow8 << 17) | dst17
        int* h_cnt  = (int*)smem;                          // NB
        int* h_base = h_cnt + NB;                          // NB+1
        int* h_gpos = h_base + NB + 1;                     // NB
        int* h_cur  = h_gpos + NB;                         // NB
        unsigned* sbuf = (unsigned*)(h_cur + NB);          // CHUNK
        unsigned short* sbkt = (unsigned short*)(sbuf + CHUNK);  // CHUNK

        const int base = half * CHUNK;
        const int cnt = min(CHUNK, GE - base);

        int srcv[CHUNK / 256], dstv[CHUNK / 256];
#pragma unroll
        for (int i = 0; i < CHUNK / 256; ++i) {
            int idx = tid + i * 256;
            if (idx < cnt) { srcv[i] = ei[base + idx]; dstv[i] = ei[GE + base + idx]; }
            else srcv[i] = -1;
        }
        for (int j = tid; j < NB; j += 256) h_cnt[j] = 0;
        __syncthreads();
#pragma unroll
        for (int i = 0; i < CHUNK / 256; ++i)
            if (srcv[i] >= 0) atomicAdd(&h_cnt[srcv[i] >> 8], 1);
        __syncthreads();
        if (tid < 64) {                      // wave0 exclusive scan of h_cnt -> h_base
            int carry = 0;
            for (int b0 = 0; b0 < NB; b0 += 64) {
                int idx = b0 + tid;
                int v = (idx < NB) ? h_cnt[idx] : 0;
                int xx = v;
#pragma unroll
                for (int off = 1; off < 64; off <<= 1) {
                    int y = __shfl_up(xx, off, 64);
                    if (tid >= off) xx += y;
                }
                if (idx < NB) h_base[idx] = carry + xx - v;
                carry += __shfl(xx, 63, 64);
            }
            if (tid == 0) h_base[NB] = carry;
        }
        __syncthreads();
        for (int j = tid; j < NB; j += 256) {
            h_cur[j] = h_base[j];
            int c = h_cnt[j];
            if (c) h_gpos[j] = atomicAdd(&bcursor[j], c);   // reserve run in bucket region
        }
        __syncthreads();
#pragma unroll
        for (int i = 0; i < CHUNK / 256; ++i)
            if (srcv[i] >= 0) {
                int b = srcv[i] >> 8;
                int p = atomicAdd(&h_cur[b], 1);
                sbuf[p] = ((unsigned)(srcv[i] & 255) << 17) | (unsigned)dstv[i];
                sbkt[p] = (unsigned short)b;
            }
        __syncthreads();
        for (int p = tid; p < cnt; p += 256) {   // coalesced run copy-out, direct-indexed
            int b = sbkt[p];
            binned[h_gpos[b] + (p - h_base[b])] = sbuf[p];
        }
    }
}

// ---------------- CSR build, pass 2: per-bucket fine scatter, LDS-staged, in-place ----------------
__global__ __launch_bounds__(1024) void fine_kernel(unsigned* __restrict__ binned,
                                                    const int* __restrict__ bcursor,
                                                    int* __restrict__ rowbeg,
                                                    int* __restrict__ rowend) {
    __shared__ unsigned sedge[BSTRIDE];
    __shared__ int n_cnt[256];
    __shared__ int n_base[256];
    __shared__ int n_cur[256];
    const int b = blockIdx.x;
    const int tid = threadIdx.x;
    const int node0 = b * 256;
    const int nn = min(256, GN - node0);
    const int beg = b * BSTRIDE;
    const int cnt = bcursor[b] - beg;
    if (tid < 256) n_cnt[tid] = 0;
    for (int p = tid; p < cnt; p += 1024) sedge[p] = binned[beg + p];
    __syncthreads();
    for (int p = tid; p < cnt; p += 1024)
        atomicAdd(&n_cnt[sedge[p] >> 17], 1);
    __syncthreads();
    if (tid < 64) {
        int carry = 0;
        for (int b0 = 0; b0 < 256; b0 += 64) {
            int idx = b0 + tid;
            int v = n_cnt[idx];
            int x = v;
#pragma unroll
            for (int off = 1; off < 64; off <<= 1) {
                int y = __shfl_up(x, off, 64);
                if (tid >= off) x += y;
            }
            n_base[idx] = carry + x - v;
            carry += __shfl(x, 63, 64);
        }
    }
    __syncthreads();
    if (tid < nn) {
        rowbeg[node0 + tid] = beg + n_base[tid];
        rowend[node0 + tid] = beg + n_base[tid] + n_cnt[tid];
    }
    if (tid < 256) n_cur[tid] = n_base[tid];
    __syncthreads();
    for (int p = tid; p < cnt; p += 1024) {
        unsigned e = sedge[p];
        int pos = atomicAdd(&n_cur[e >> 17], 1);
        binned[beg + pos] = e & 0x1FFFFu;            // plain dst, node-grouped
    }
}

// ---------------- per-node softmax + weighted aggregation (bf16 h) ----------------
// (unchanged -- pinned at random-gather memory-path ceiling; serves as control)
__global__ __launch_bounds__(256) void aggregate_kernel(const uint4* __restrict__ h4,
                                                        const float* __restrict__ s_l,
                                                        const float* __restrict__ s_r,
                                                        const int* __restrict__ rowbeg,
                                                        const int* __restrict__ rowend,
                                                        const int* __restrict__ adj,
                                                        float* __restrict__ out) {
    __shared__ int   s_dst[4][CAP];
    __shared__ float s_w[4][CAP];               // e, later exp(e-m)
    const int wid = threadIdx.x >> 6, lane = threadIdx.x & 63;
    const int node = blockIdx.x * 4 + wid;      // grid = GN/4 exactly
    const int beg = rowbeg[node], end = rowend[node];
    const int deg = end - beg;
    const float sl = s_l[node];

    float m = -1e30f;
    for (int j = lane; j < deg; j += 64) {
        int dst = adj[beg + j];
        float e = sl + s_r[dst];
        e = (e >= 0.f) ? e : 0.2f * e;
        if (j < CAP) { s_dst[wid][j] = dst; s_w[wid][j] = e; }
        m = fmaxf(m, e);
    }
#pragma unroll
    for (int off = 1; off < 64; off <<= 1)
        m = fmaxf(m, __shfl_xor(m, off, 64));
    __syncthreads();

    const int n2 = deg < CAP ? deg : CAP;
    float d = 0.f;
    for (int j = lane; j < n2; j += 64) {
        float w = __expf(s_w[wid][j] - m);
        s_w[wid][j] = w;
        d += w;
    }
    for (int j = CAP + lane; j < deg; j += 64) {   // deg > CAP spill (rare)
        int dst = adj[beg + j];
        float e = sl + s_r[dst];
        e = (e >= 0.f) ? e : 0.2f * e;
        d += __expf(e - m);
    }
#pragma unroll
    for (int off = 1; off < 64; off <<= 1)
        d += __shfl_xor(d, off, 64);
    const float inv = 1.f / (d + 1e-16f);
    __syncthreads();

    const int fl = lane & 15, grp = lane >> 4;
    f32x4 accA = {0.f, 0.f, 0.f, 0.f}, accB = {0.f, 0.f, 0.f, 0.f};
    int j = 0;
#pragma unroll 2
    for (; j < n2; j += 8) {
        int j0 = j + grp, j1 = j + grp + 4;
        bool a0 = j0 < n2, a1 = j1 < n2;
        int   d0 = s_dst[wid][a0 ? j0 : 0];
        int   d1 = s_dst[wid][a1 ? j1 : 0];
        float w0 = a0 ? s_w[wid][j0] : 0.f;
        float w1 = a1 ? s_w[wid][j1] : 0.f;
        uint4 v0 = h4[(size_t)d0 * 16 + fl];
        uint4 v1 = h4[(size_t)d1 * 16 + fl];
        accA.x += w0 * __uint_as_float(v0.x << 16);
        accA.y += w0 * __uint_as_float(v0.x & 0xffff0000u);
        accA.z += w0 * __uint_as_float(v0.y << 16);
        accA.w += w0 * __uint_as_float(v0.y & 0xffff0000u);
        accB.x += w0 * __uint_as_float(v0.z << 16);
        accB.y += w0 * __uint_as_float(v0.z & 0xffff0000u);
        accB.z += w0 * __uint_as_float(v0.w << 16);
        accB.w += w0 * __uint_as_float(v0.w & 0xffff0000u);
        accA.x += w1 * __uint_as_float(v1.x << 16);
        accA.y += w1 * __uint_as_float(v1.x & 0xffff0000u);
        accA.z += w1 * __uint_as_float(v1.y << 16);
        accA.w += w1 * __uint_as_float(v1.y & 0xffff0000u);
        accB.x += w1 * __uint_as_float(v1.z << 16);
        accB.y += w1 * __uint_as_float(v1.z & 0xffff0000u);
        accB.z += w1 * __uint_as_float(v1.w << 16);
        accB.w += w1 * __uint_as_float(v1.w & 0xffff0000u);
    }
    for (; j < deg; j += 4) {                     // deg > CAP spill (rare): recompute weights
        int jj = j + grp;
        bool act = jj < deg;
        int dst = act ? adj[beg + jj] : 0;
        float e = sl + s_r[dst];
        e = (e >= 0.f) ? e : 0.2f * e;
        float w = act ? __expf(e - m) : 0.f;
        uint4 v = h4[(size_t)dst * 16 + fl];
        accA.x += w * __uint_as_float(v.x << 16);
        accA.y += w * __uint_as_float(v.x & 0xffff0000u);
        accA.z += w * __uint_as_float(v.y << 16);
        accA.w += w * __uint_as_float(v.y & 0xffff0000u);
        accB.x += w * __uint_as_float(v.z << 16);
        accB.y += w * __uint_as_float(v.z & 0xffff0000u);
        accB.z += w * __uint_as_float(v.w << 16);
        accB.w += w * __uint_as_float(v.w & 0xffff0000u);
    }

#pragma unroll
    for (int off = 16; off < 64; off <<= 1) {
        accA.x += __shfl_xor(accA.x, off, 64);
        accA.y += __shfl_xor(accA.y, off, 64);
        accA.z += __shfl_xor(accA.z, off, 64);
        accA.w += __shfl_xor(accA.w, off, 64);
        accB.x += __shfl_xor(accB.x, off, 64);
        accB.y += __shfl_xor(accB.y, off, 64);
        accB.z += __shfl_xor(accB.z, off, 64);
        accB.w += __shfl_xor(accB.w, off, 64);
    }
    if (lane < 16) {
        float* orow = out + (size_t)node * 128 + fl * 8;
        accA.x *= inv; accA.y *= inv; accA.z *= inv; accA.w *= inv;
        accB.x *= inv; accB.y *= inv; accB.z *= inv; accB.w *= inv;
        *(f32x4*)orow       = accA;
        *(f32x4*)(orow + 4) = accB;
    }
}

extern "C" void kernel_launch(void* const* d_in, const int* in_sizes, int n_in,
                              void* d_out, int out_size, void* d_ws, size_t ws_size,
                              hipStream_t stream) {
    const float* x  = (const float*)d_in[0];
    const int*   ei = (const int*)d_in[1];      // [0,E) = src, [E,2E) = dst
    const float* w  = (const float*)d_in[2];
    const float* a  = (const float*)d_in[3];
    float* out = (float*)d_out;

    // workspace layout (4-byte words)
    unsigned short* hq = (unsigned short*)d_ws;             // GN*128 bf16
    float* s_l     = (float*)(hq + (size_t)GN * 128);       // GN
    float* s_r     = s_l + GN;                              // GN
    int*   bcursor = (int*)(s_r + GN);                      // NB
    int*   rowbeg  = bcursor + NB;                          // GN
    int*   rowend  = rowbeg + GN;                           // GN
    unsigned* binned = (unsigned*)(rowend + GN);            // NB * BSTRIDE
    unsigned short* wT = (unsigned short*)(binned + (size_t)NB * BSTRIDE);  // 128*256 bf16

    wprep_kernel<<<34 + (2 * GN / 4 + 255) / 256, 256, 0, stream>>>(w, wT, bcursor, s_l);
    gemmbin_kernel<<<2 * GBLK, 256, 0, stream>>>(x, wT, a, hq, s_l, s_r, ei, bcursor, binned);
    fine_kernel<<<NB, 1024, 0, stream>>>(binned, bcursor, rowbeg, rowend);
    aggregate_kernel<<<GN / 4, 256, 0, stream>>>((const uint4*)hq, s_l, s_r, rowbeg, rowend,
                                                 (const int*)binned, out);
}

// Round 6
// 364.216 us; speedup vs baseline: 1.0062x; 1.0062x over previous
//
#include <hip/hip_runtime.h>

#define GN 100000
#define GE 3200000
#define CAP 128
#define NB 391          // coarse buckets: src >> 8, 256 nodes each
#define CHUNK 4096      // edges per bin-pass block
#define BSTRIDE 9216    // fixed bucket stride: mean 8192, sigma ~90, 11-sigma margin
#define GBLK 782        // gemm blocks = ceil(GN/128) == bin blocks = ceil(GE/CHUNK)
#define EPT 18          // ceil(BSTRIDE / 512) entries per thread in aggfine CSR build

typedef __attribute__((ext_vector_type(8))) short bf16x8;
typedef __attribute__((ext_vector_type(4))) float f32x4;

__device__ __forceinline__ unsigned short f2bf(float f) {
    unsigned u = __float_as_uint(f);
    u += 0x7fffu + ((u >> 16) & 1u);          // RNE
    return (unsigned short)(u >> 16);
}
// packed RNE f32x2 -> bf16x2 (1 VALU op vs ~7 for two f2bf)
__device__ __forceinline__ unsigned cvtpk(float lo, float hi) {
    unsigned r;
    asm("v_cvt_pk_bf16_f32 %0, %1, %2" : "=v"(r) : "v"(lo), "v"(hi));
    return r;
}

// ---------------- W prep + bcursor init + s_l/s_r zero (replaces memset) ----------------
__global__ __launch_bounds__(256) void wprep_kernel(const float* __restrict__ w,
                                                    unsigned short* __restrict__ wT,
                                                    int* __restrict__ bcursor,
                                                    float* __restrict__ s_l) {
    if (blockIdx.x < 32) {                          // w fp32 [256][128] -> wT bf16 [128][256]
        int flat4 = blockIdx.x * 256 + threadIdx.x; // 0..8191
        int k  = flat4 >> 5;
        int n4 = (flat4 & 31) * 4;
        float4 v = ((const float4*)w)[flat4];
        wT[(size_t)(n4 + 0) * 256 + k] = f2bf(v.x);
        wT[(size_t)(n4 + 1) * 256 + k] = f2bf(v.y);
        wT[(size_t)(n4 + 2) * 256 + k] = f2bf(v.z);
        wT[(size_t)(n4 + 3) * 256 + k] = f2bf(v.w);
    } else if (blockIdx.x < 34) {                   // bucket cursor init (fixed-stride bases)
        int j = (blockIdx.x - 32) * 256 + threadIdx.x;
        if (j < NB) bcursor[j] = j * BSTRIDE;
    } else {                                        // zero s_l,s_r (contiguous 2*GN floats)
        int i = (blockIdx.x - 34) * 256 + threadIdx.x;
        if (i < 2 * GN / 4) {
            float4 z = {0.f, 0.f, 0.f, 0.f};
            ((float4*)s_l)[i] = z;
        }
    }
}

// ---------------- FAT kernel: gemm (even blocks) || bin (odd blocks) ----------------
__global__ __launch_bounds__(256) void gemmbin_kernel(const float* __restrict__ x,
                                                      const unsigned short* __restrict__ wT,
                                                      const float* __restrict__ a,
                                                      unsigned short* __restrict__ hq,
                                                      float* __restrict__ s_l,
                                                      float* __restrict__ s_r,
                                                      const int* __restrict__ ei,
                                                      int* __restrict__ bcursor,
                                                      unsigned* __restrict__ binned) {
    __shared__ __align__(16) char smem[30848];      // max(gemm 20480, bin 30836)
    const int half = blockIdx.x >> 1;
    const int tid = threadIdx.x;

    if ((blockIdx.x & 1) == 0) {
        // ================= GEMM path: h = x @ W, scores fused =================
        unsigned short (*As)[128][40] = (unsigned short (*)[128][40])smem;
        const int lane = tid & 63, wid = tid >> 6;
        const int l16  = lane & 15, quad = lane >> 4;
        const int wm   = (wid >> 1) * 64, wn = (wid & 1) * 64;
        const int bm   = half * 128;

        f32x4 acc[4][4] = {};

        const int arow = tid >> 1, ahalf = tid & 1;
        int gr = bm + arow; if (gr >= GN) gr = GN - 1;   // clamp loads; stores guarded
        const float* xrow = x + (size_t)gr * 256 + ahalf * 16;

        {   // prologue: stage k0=0 tile into As[0]
            float4 f0 = *(const float4*)(xrow + 0);
            float4 f1 = *(const float4*)(xrow + 4);
            float4 f2 = *(const float4*)(xrow + 8);
            float4 f3 = *(const float4*)(xrow + 12);
            uint4 u0, u1;
            u0.x = cvtpk(f0.x, f0.y); u0.y = cvtpk(f0.z, f0.w);
            u0.z = cvtpk(f1.x, f1.y); u0.w = cvtpk(f1.z, f1.w);
            u1.x = cvtpk(f2.x, f2.y); u1.y = cvtpk(f2.z, f2.w);
            u1.z = cvtpk(f3.x, f3.y); u1.w = cvtpk(f3.z, f3.w);
            *(uint4*)&As[0][arow][ahalf * 16]     = u0;
            *(uint4*)&As[0][arow][ahalf * 16 + 8] = u1;
        }
        bf16x8 bcur[4];
#pragma unroll
        for (int t = 0; t < 4; ++t)
            bcur[t] = *(const bf16x8*)(wT + (size_t)(wn + t * 16 + l16) * 256 + quad * 8);
        __syncthreads();

#pragma unroll
        for (int ks = 0; ks < 8; ++ks) {
            const int cb = ks & 1;
            bf16x8 bnxt[4];
            uint4 u0, u1;
            if (ks < 7) {
                const int k1 = (ks + 1) * 32;
#pragma unroll
                for (int t = 0; t < 4; ++t)
                    bnxt[t] = *(const bf16x8*)(wT + (size_t)(wn + t * 16 + l16) * 256 + k1 + quad * 8);
                float4 f0 = *(const float4*)(xrow + k1);
                float4 f1 = *(const float4*)(xrow + k1 + 4);
                float4 f2 = *(const float4*)(xrow + k1 + 8);
                float4 f3 = *(const float4*)(xrow + k1 + 12);
                u0.x = cvtpk(f0.x, f0.y); u0.y = cvtpk(f0.z, f0.w);
                u0.z = cvtpk(f1.x, f1.y); u0.w = cvtpk(f1.z, f1.w);
                u1.x = cvtpk(f2.x, f2.y); u1.y = cvtpk(f2.z, f2.w);
                u1.z = cvtpk(f3.x, f3.y); u1.w = cvtpk(f3.z, f3.w);
            }
            bf16x8 af[4];
#pragma unroll
            for (int t = 0; t < 4; ++t)
                af[t] = *(const bf16x8*)&As[cb][wm + t * 16 + l16][quad * 8];
#pragma unroll
            for (int ti = 0; ti < 4; ++ti)
#pragma unroll
                for (int tj = 0; tj < 4; ++tj)
                    acc[ti][tj] = __builtin_amdgcn_mfma_f32_16x16x32_bf16(af[ti], bcur[tj], acc[ti][tj], 0, 0, 0);
            if (ks < 7) {
                *(uint4*)&As[cb ^ 1][arow][ahalf * 16]     = u0;
                *(uint4*)&As[cb ^ 1][arow][ahalf * 16 + 8] = u1;
                __syncthreads();
#pragma unroll
                for (int t = 0; t < 4; ++t) bcur[t] = bnxt[t];
            }
        }

        float alv[4], arv[4];
#pragma unroll
        for (int tj = 0; tj < 4; ++tj) {
            alv[tj] = a[wn + tj * 16 + l16];
            arv[tj] = a[128 + wn + tj * 16 + l16];
        }
#pragma unroll
        for (int ti = 0; ti < 4; ++ti) {
            float slp[4], srp[4];
#pragma unroll
            for (int r = 0; r < 4; ++r) {
                int row = bm + wm + ti * 16 + quad * 4 + r;
                float v0 = acc[ti][0][r], v1 = acc[ti][1][r], v2 = acc[ti][2][r], v3 = acc[ti][3][r];
                if (row < GN) {
                    unsigned short* hp = hq + (size_t)row * 128 + wn + l16;
                    hp[0]  = f2bf(v0);
                    hp[16] = f2bf(v1);
                    hp[32] = f2bf(v2);
                    hp[48] = f2bf(v3);
                }
                slp[r] = v0 * alv[0] + v1 * alv[1] + v2 * alv[2] + v3 * alv[3];
                srp[r] = v0 * arv[0] + v1 * arv[1] + v2 * arv[2] + v3 * arv[3];
            }
#pragma unroll
            for (int off = 1; off < 16; off <<= 1)
#pragma unroll
                for (int r = 0; r < 4; ++r) {
                    slp[r] += __shfl_xor(slp[r], off, 64);
                    srp[r] += __shfl_xor(srp[r], off, 64);
                }
            if (l16 == 0) {
#pragma unroll
                for (int r = 0; r < 4; ++r) {
                    int row = bm + wm + ti * 16 + quad * 4 + r;
                    if (row < GN) {
                        atomicAdd(&s_l[row], slp[r]);
                        atomicAdd(&s_r[row], srp[r]);
                    }
                }
            }
        }
    } else {
        // ================= BIN path: per-chunk counting sort -> coalesced runs =================
        // entry = (srcLow8 << 17) | dst17
        int* h_cnt  = (int*)smem;                          // NB
        int* h_base = h_cnt + NB;                          // NB+1
        int* h_gpos = h_base + NB + 1;                     // NB
        int* h_cur  = h_gpos + NB;                         // NB
        unsigned* sbuf = (unsigned*)(h_cur + NB);          // CHUNK
        unsigned short* sbkt = (unsigned short*)(sbuf + CHUNK);  // CHUNK

        const int base = half * CHUNK;
        const int cnt = min(CHUNK, GE - base);

        int srcv[CHUNK / 256], dstv[CHUNK / 256];
#pragma unroll
        for (int i = 0; i < CHUNK / 256; ++i) {
            int idx = tid + i * 256;
            if (idx < cnt) { srcv[i] = ei[base + idx]; dstv[i] = ei[GE + base + idx]; }
            else srcv[i] = -1;
        }
        for (int j = tid; j < NB; j += 256) h_cnt[j] = 0;
        __syncthreads();
#pragma unroll
        for (int i = 0; i < CHUNK / 256; ++i)
            if (srcv[i] >= 0) atomicAdd(&h_cnt[srcv[i] >> 8], 1);
        __syncthreads();
        if (tid < 64) {                      // wave0 exclusive scan of h_cnt -> h_base
            int carry = 0;
            for (int b0 = 0; b0 < NB; b0 += 64) {
                int idx = b0 + tid;
                int v = (idx < NB) ? h_cnt[idx] : 0;
                int xx = v;
#pragma unroll
                for (int off = 1; off < 64; off <<= 1) {
                    int y = __shfl_up(xx, off, 64);
                    if (tid >= off) xx += y;
                }
                if (idx < NB) h_base[idx] = carry + xx - v;
                carry += __shfl(xx, 63, 64);
            }
            if (tid == 0) h_base[NB] = carry;
        }
        __syncthreads();
        for (int j = tid; j < NB; j += 256) {
            h_cur[j] = h_base[j];
            int c = h_cnt[j];
            if (c) h_gpos[j] = atomicAdd(&bcursor[j], c);   // reserve run in bucket region
        }
        __syncthreads();
#pragma unroll
        for (int i = 0; i < CHUNK / 256; ++i)
            if (srcv[i] >= 0) {
                int b = srcv[i] >> 8;
                int p = atomicAdd(&h_cur[b], 1);
                sbuf[p] = ((unsigned)(srcv[i] & 255) << 17) | (unsigned)dstv[i];
                sbkt[p] = (unsigned short)b;
            }
        __syncthreads();
        for (int p = tid; p < cnt; p += 256) {   // coalesced run copy-out, direct-indexed
            int b = sbkt[p];
            binned[h_gpos[b] + (p - h_base[b])] = sbuf[p];
        }
    }
}

// ---------------- FUSED fine + aggregate: one block per bucket (256 nodes, 512 thr) ----------------
// CSR build: bucket window -> registers (EPT/thread), hist+scan, scatter node-sorted dst into
// LDS sedge. Aggregation then runs with adjacency in LDS -- fine_kernel's global round-trip
// (binned rewrite + adj re-read + rowbeg/rowend) is gone.
__global__ __launch_bounds__(512) void aggfine_kernel(const uint4* __restrict__ h4,
                                                      const float* __restrict__ s_l,
                                                      const float* __restrict__ s_r,
                                                      const unsigned* __restrict__ binned,
                                                      const int* __restrict__ bcursor,
                                                      float* __restrict__ out) {
    __shared__ unsigned sedge[BSTRIDE];       // 36864 B: node-grouped dst lists
    __shared__ int n_cnt[256];
    __shared__ int n_base[256];
    __shared__ int n_cur[256];
    __shared__ float s_w[8][CAP];             // wave-private softmax weights
    const int b    = blockIdx.x;
    const int tid  = threadIdx.x;
    const int wid  = tid >> 6, lane = tid & 63;
    const int node0 = b * 256;
    const int beg  = b * BSTRIDE;
    const int cnt  = min(bcursor[b] - beg, BSTRIDE);

    // ---- CSR build in LDS ----
    unsigned ev[EPT];
    if (tid < 256) n_cnt[tid] = 0;
    __syncthreads();
#pragma unroll
    for (int i = 0; i < EPT; ++i) {
        int p = tid + i * 512;
        if (p < cnt) {
            ev[i] = binned[beg + p];
            atomicAdd(&n_cnt[ev[i] >> 17], 1);
        }
    }
    __syncthreads();
    if (tid < 64) {                           // wave0 exclusive scan of n_cnt -> n_base
        int carry = 0;
        for (int b0 = 0; b0 < 256; b0 += 64) {
            int idx = b0 + tid;
            int v = n_cnt[idx];
            int x = v;
#pragma unroll
            for (int off = 1; off < 64; off <<= 1) {
                int y = __shfl_up(x, off, 64);
                if (tid >= off) x += y;
            }
            n_base[idx] = carry + x - v;
            carry += __shfl(x, 63, 64);
        }
    }
    __syncthreads();
    if (tid < 256) n_cur[tid] = n_base[tid];
    __syncthreads();
#pragma unroll
    for (int i = 0; i < EPT; ++i) {
        int p = tid + i * 512;
        if (p < cnt) {
            unsigned e = ev[i];
            int pos = atomicAdd(&n_cur[e >> 17], 1);
            sedge[pos] = e & 0x1FFFFu;        // plain dst, node-grouped
        }
    }
    __syncthreads();

    // ---- per-node softmax + weighted aggregation (wave-private; NO barriers below) ----
    const int fl = lane & 15, grp = lane >> 4;
    for (int k = 0; k < 32; ++k) {
        const int n = wid * 32 + k;
        const int node = node0 + n;
        if (node >= GN) break;                // wave-uniform
        const int nb  = n_base[n];
        const int deg = n_cnt[n];
        const float sl = s_l[node];

        float m = -1e30f;
        for (int j = lane; j < deg; j += 64) {
            int dst = (int)sedge[nb + j];
            float e = sl + s_r[dst];
            e = (e >= 0.f) ? e : 0.2f * e;
            if (j < CAP) s_w[wid][j] = e;
            m = fmaxf(m, e);
        }
#pragma unroll
        for (int off = 1; off < 64; off <<= 1)
            m = fmaxf(m, __shfl_xor(m, off, 64));

        const int n2 = deg < CAP ? deg : CAP;
        float d = 0.f;
        for (int j = lane; j < n2; j += 64) {
            float w = __expf(s_w[wid][j] - m);
            s_w[wid][j] = w;
            d += w;
        }
        for (int j = CAP + lane; j < deg; j += 64) {   // deg > CAP spill (rare)
            int dst = (int)sedge[nb + j];
            float e = sl + s_r[dst];
            e = (e >= 0.f) ? e : 0.2f * e;
            d += __expf(e - m);
        }
#pragma unroll
        for (int off = 1; off < 64; off <<= 1)
            d += __shfl_xor(d, off, 64);
        const float inv = 1.f / (d + 1e-16f);

        f32x4 accA = {0.f, 0.f, 0.f, 0.f}, accB = {0.f, 0.f, 0.f, 0.f};
        int j = 0;
#pragma unroll 2
        for (; j < n2; j += 8) {
            int j0 = j + grp, j1 = j + grp + 4;
            bool a0 = j0 < n2, a1 = j1 < n2;
            int   d0 = (int)sedge[nb + (a0 ? j0 : 0)];
            int   d1 = (int)sedge[nb + (a1 ? j1 : 0)];
            float w0 = a0 ? s_w[wid][j0] : 0.f;
            float w1 = a1 ? s_w[wid][j1] : 0.f;
            uint4 v0 = h4[(size_t)d0 * 16 + fl];
            uint4 v1 = h4[(size_t)d1 * 16 + fl];
            accA.x += w0 * __uint_as_float(v0.x << 16);
            accA.y += w0 * __uint_as_float(v0.x & 0xffff0000u);
            accA.z += w0 * __uint_as_float(v0.y << 16);
            accA.w += w0 * __uint_as_float(v0.y & 0xffff0000u);
            accB.x += w0 * __uint_as_float(v0.z << 16);
            accB.y += w0 * __uint_as_float(v0.z & 0xffff0000u);
            accB.z += w0 * __uint_as_float(v0.w << 16);
            accB.w += w0 * __uint_as_float(v0.w & 0xffff0000u);
            accA.x += w1 * __uint_as_float(v1.x << 16);
            accA.y += w1 * __uint_as_float(v1.x & 0xffff0000u);
            accA.z += w1 * __uint_as_float(v1.y << 16);
            accA.w += w1 * __uint_as_float(v1.y & 0xffff0000u);
            accB.x += w1 * __uint_as_float(v1.z << 16);
            accB.y += w1 * __uint_as_float(v1.z & 0xffff0000u);
            accB.z += w1 * __uint_as_float(v1.w << 16);
            accB.w += w1 * __uint_as_float(v1.w & 0xffff0000u);
        }
        for (; j < deg; j += 4) {                     // deg > CAP spill (rare): recompute weights
            int jj = j + grp;
            bool act = jj < deg;
            int dst = (int)sedge[nb + (act ? jj : 0)];
            float e = sl + s_r[dst];
            e = (e >= 0.f) ? e : 0.2f * e;
            float w = act ? __expf(e - m) : 0.f;
            uint4 v = h4[(size_t)dst * 16 + fl];
            accA.x += w * __uint_as_float(v.x << 16);
            accA.y += w * __uint_as_float(v.x & 0xffff0000u);
            accA.z += w * __uint_as_float(v.y << 16);
            accA.w += w * __uint_as_float(v.y & 0xffff0000u);
            accB.x += w * __uint_as_float(v.z << 16);
            accB.y += w * __uint_as_float(v.z & 0xffff0000u);
            accB.z += w * __uint_as_float(v.w << 16);
            accB.w += w * __uint_as_float(v.w & 0xffff0000u);
        }

#pragma unroll
        for (int off = 16; off < 64; off <<= 1) {
            accA.x += __shfl_xor(accA.x, off, 64);
            accA.y += __shfl_xor(accA.y, off, 64);
            accA.z += __shfl_xor(accA.z, off, 64);
            accA.w += __shfl_xor(accA.w, off, 64);
            accB.x += __shfl_xor(accB.x, off, 64);
            accB.y += __shfl_xor(accB.y, off, 64);
            accB.z += __shfl_xor(accB.z, off, 64);
            accB.w += __shfl_xor(accB.w, off, 64);
        }
        if (lane < 16) {
            float* orow = out + (size_t)node * 128 + fl * 8;
            accA.x *= inv; accA.y *= inv; accA.z *= inv; accA.w *= inv;
            accB.x *= inv; accB.y *= inv; accB.z *= inv; accB.w *= inv;
            *(f32x4*)orow       = accA;
            *(f32x4*)(orow + 4) = accB;
        }
    }
}

extern "C" void kernel_launch(void* const* d_in, const int* in_sizes, int n_in,
                              void* d_out, int out_size, void* d_ws, size_t ws_size,
                              hipStream_t stream) {
    const float* x  = (const float*)d_in[0];
    const int*   ei = (const int*)d_in[1];      // [0,E) = src, [E,2E) = dst
    const float* w  = (const float*)d_in[2];
    const float* a  = (const float*)d_in[3];
    float* out = (float*)d_out;

    // workspace layout (4-byte words)
    unsigned short* hq = (unsigned short*)d_ws;             // GN*128 bf16
    float* s_l     = (float*)(hq + (size_t)GN * 128);       // GN
    float* s_r     = s_l + GN;                              // GN
    int*   bcursor = (int*)(s_r + GN);                      // NB
    unsigned* binned = (unsigned*)(bcursor + NB);           // NB * BSTRIDE
    unsigned short* wT = (unsigned short*)(binned + (size_t)NB * BSTRIDE);  // 128*256 bf16

    wprep_kernel<<<34 + (2 * GN / 4 + 255) / 256, 256, 0, stream>>>(w, wT, bcursor, s_l);
    gemmbin_kernel<<<2 * GBLK, 256, 0, stream>>>(x, wT, a, hq, s_l, s_r, ei, bcursor, binned);
    aggfine_kernel<<<NB, 512, 0, stream>>>((const uint4*)hq, s_l, s_r, binned, bcursor, out);
}